// Round 1
// baseline (301.629 us; speedup 1.0000x reference)
//
#include <hip/hip_runtime.h>

// SpatialCorrelationSampler: out[b, (dy+4)*9+(dx+4), y, x] =
//   sum_c f0[b,c,y,x] * f1[b,c,y+dy,x+dx], dy,dx in [-4,4], zero-padded OOB.
// B=4 C=256 H=96 W=160 -> out (4,81,96,160) fp32.
//
// Design: block = 9 waves (576 thr) over a 16x32 output tile; wave w owns
// dy = w-4. f1 window (24 rows x 40 cols per channel) staged in LDS with row
// stride 44 floats (16B-aligned + conflict-free b128 pattern). Each lane owns
// 8 consecutive x (RX=8): per (channel,dy) 4x ds_read_b128 (16 f1 vals) feed
// 72 FMAs -> 0.89 B/MAC LDS traffic. f0 read direct from global (L1-resident).
// C split 4-ways across blocks (grid 120x4) for occupancy; partials combined
// with fp32 atomicAdd after an LDS transpose for coalesced stores.

#define Bn 4
#define Cn 256
#define Hn 96
#define Wn 160
#define HWn (Hn * Wn)
#define NP 81
#define TY 16
#define TX 32
#define NCSPLIT 4
#define CPB (Cn / NCSPLIT)   // 64 channels per block
#define CCH 4                // channels staged per round
#define NSTAGE (CPB / CCH)   // 16
#define WROWS (TY + 8)       // 24
#define WCOLS (TX + 8)       // 40
#define SEGS (WCOLS / 4)     // 10 float4 segments per row
#define LROW 44              // padded LDS row stride (floats)
#define F1C (WROWS * LROW)   // 1056 floats per staged channel
#define NCOPY (CCH * WROWS * SEGS)  // 960 float4 copies per stage
#define NT 576

__global__ __launch_bounds__(NT) void corr_kernel(const float* __restrict__ f0,
                                                  const float* __restrict__ f1,
                                                  float* __restrict__ out) {
    __shared__ __align__(16) float lds[4608];  // max(4*1056=4224 stage, 9*512=4608 transpose)

    const int tid  = threadIdx.x;
    const int wave = tid >> 6;      // 0..8  (dy = wave-4)
    const int lane = tid & 63;
    const int r    = lane >> 2;     // 0..15 tile row
    const int g    = lane & 3;      // 0..3  col group of 8 px

    const int tile = blockIdx.x;    // 0..119
    const int b    = tile / 30;
    const int rem  = tile % 30;
    const int ty   = rem / 5;
    const int tx   = rem - ty * 5;
    const int y0   = ty * TY;
    const int x0   = tx * TX;
    const int c0   = blockIdx.y * CPB;

    // ---- staging assignment (constant across stages): <=2 float4 copies/thread
    int  lidx[2];
    int  gidx[2];
    bool gval[2];
    int  nc = 0;
    for (int t = tid; t < NCOPY; t += NT) {
        int cc  = t / (WROWS * SEGS);
        int rm  = t - cc * (WROWS * SEGS);
        int rr  = rm / SEGS;
        int seg = rm - rr * SEGS;
        int gy  = y0 - 4 + rr;
        int gx  = x0 - 4 + seg * 4;            // multiple of 4; row segs all-in or all-out
        lidx[nc] = (cc * F1C + rr * LROW + seg * 4) >> 2;
        bool v   = (gy >= 0) && (gy < Hn) && (gx >= 0) && (gx < Wn);
        gidx[nc] = v ? ((((b * Cn + c0 + cc) * Hn + gy) * Wn + gx) >> 2) : 0;
        gval[nc] = v;
        nc++;
    }

    float acc[9][8];
#pragma unroll
    for (int i = 0; i < 9; ++i) {
#pragma unroll
        for (int j = 0; j < 8; ++j) acc[i][j] = 0.f;
    }

    const int f0base = ((b * Cn + c0) * Hn + y0 + r) * Wn + x0 + g * 8;
    const float4* __restrict__ f1v = (const float4*)f1;
    float4* lv = (float4*)lds;

    for (int stage = 0; stage < NSTAGE; ++stage) {
        __syncthreads();  // previous compute done reading LDS
#pragma unroll
        for (int i = 0; i < 2; ++i) {
            if (i < nc) {
                float4 v = make_float4(0.f, 0.f, 0.f, 0.f);
                if (gval[i]) v = f1v[gidx[i] + stage * (CCH * HWn / 4)];
                lv[lidx[i]] = v;
            }
        }
        __syncthreads();

#pragma unroll
        for (int cc = 0; cc < CCH; ++cc) {
            const float* f0p = f0 + f0base + (stage * CCH + cc) * HWn;
            float4 a0 = *(const float4*)(f0p);
            float4 a1 = *(const float4*)(f0p + 4);
            const float* wr = &lds[cc * F1C + (r + wave) * LROW + g * 8];
            float4 w0 = *(const float4*)(wr);
            float4 w1 = *(const float4*)(wr + 4);
            float4 w2 = *(const float4*)(wr + 8);
            float4 w3 = *(const float4*)(wr + 12);
            float av[8]  = {a0.x, a0.y, a0.z, a0.w, a1.x, a1.y, a1.z, a1.w};
            float wv[16] = {w0.x, w0.y, w0.z, w0.w, w1.x, w1.y, w1.z, w1.w,
                            w2.x, w2.y, w2.z, w2.w, w3.x, w3.y, w3.z, w3.w};
#pragma unroll
            for (int dx = 0; dx < 9; ++dx) {
#pragma unroll
                for (int rx = 0; rx < 8; ++rx)
                    acc[dx][rx] = fmaf(av[rx], wv[rx + dx], acc[dx][rx]);
            }
        }
    }

    __syncthreads();  // all waves done with f1 buffer; reuse LDS for transpose

    // epilogue: per dx, transpose wave's 16x32 tile through LDS, coalesced atomicAdd
    float* tp = &lds[wave * 512];   // per-wave private 512-float region
    for (int dx = 0; dx < 9; ++dx) {
        *(float4*)&tp[r * 32 + g * 8]     = make_float4(acc[dx][0], acc[dx][1], acc[dx][2], acc[dx][3]);
        *(float4*)&tp[r * 32 + g * 8 + 4] = make_float4(acc[dx][4], acc[dx][5], acc[dx][6], acc[dx][7]);
        __syncthreads();  // conservative; regions are wave-private (in-wave DS is in-order)
        const int p = wave * 9 + dx;
        const int obase = ((b * NP + p) * Hn + y0) * Wn + x0;
#pragma unroll
        for (int k = 0; k < 8; ++k) {
            int idx = k * 64 + lane;
            float v = tp[idx];
            int rr2 = idx >> 5;
            int xx  = idx & 31;
            atomicAdd(&out[obase + rr2 * Wn + xx], v);
        }
        __syncthreads();
    }
}

__global__ void zero_kernel(float4* __restrict__ o, int n4) {
    int i = blockIdx.x * blockDim.x + threadIdx.x;
    if (i < n4) o[i] = make_float4(0.f, 0.f, 0.f, 0.f);
}

extern "C" void kernel_launch(void* const* d_in, const int* in_sizes, int n_in,
                              void* d_out, int out_size, void* d_ws, size_t ws_size,
                              hipStream_t stream) {
    const float* f0 = (const float*)d_in[0];
    const float* f1 = (const float*)d_in[1];
    float* out = (float*)d_out;

    const int n4 = Bn * NP * Hn * Wn / 4;  // 1,244,160 float4s
    zero_kernel<<<(n4 + 255) / 256, 256, 0, stream>>>((float4*)out, n4);
    corr_kernel<<<dim3(120, NCSPLIT), NT, 0, stream>>>(f0, f1, out);
}